// Round 1
// baseline (1424.733 us; speedup 1.0000x reference)
//
#include <hip/hip_runtime.h>
#include <math.h>

#define DIN 128   // D_IN == D_HID == 128
#define NCLS 64

// ---------------- small elementwise kernels ----------------

__global__ void fill_ones_k(float* __restrict__ p, int n) {
    int i = blockIdx.x * 256 + threadIdx.x;
    if (i < n) p[i] = 1.0f;
}

__global__ void deg_count_k(const int* __restrict__ ei, float* __restrict__ deg, int E) {
    int e = blockIdx.x * 256 + threadIdx.x;
    if (e < E) atomicAdd(&deg[ei[E + e]], 1.0f);
}

__global__ void rsqrt_k(float* __restrict__ p, int n) {
    int i = blockIdx.x * 256 + threadIdx.x;
    if (i < n) p[i] = rsqrtf(p[i]);
}

// ---------------- tiled fp32 GEMM: C[N,BN] = A[N,128] @ B[128,BN] ----------------
// block = 256 threads, 64 rows per block, K = 128 (full), B fully in LDS.

template<int BN>
__global__ __launch_bounds__(256) void gemm_k(const float* __restrict__ A,
                                              const float* __restrict__ B,
                                              float* __restrict__ Cout, int N) {
    __shared__ float As[64][DIN + 1];          // +1 pad: A-col reads -> 2-way max
    __shared__ __align__(16) float Bs[DIN][BN];
    const int tid  = threadIdx.x;
    const int row0 = blockIdx.x * 64;

    // stage B (128 x BN) via float4
    {
        const float4* B4  = (const float4*)B;
        float4*       Bs4 = (float4*)&Bs[0][0];
        constexpr int nb4 = DIN * BN / 4;
        for (int i = tid; i < nb4; i += 256) Bs4[i] = B4[i];
    }
    // stage A tile (64 x 128), zero-fill tail rows
    for (int i = tid; i < 64 * (DIN / 4); i += 256) {
        int r  = i >> 5;            // DIN/4 == 32
        int c4 = i & 31;
        int gr = row0 + r;
        float4 v = make_float4(0.f, 0.f, 0.f, 0.f);
        if (gr < N) v = ((const float4*)A)[gr * (DIN / 4) + c4];
        As[r][c4 * 4 + 0] = v.x;
        As[r][c4 * 4 + 1] = v.y;
        As[r][c4 * 4 + 2] = v.z;
        As[r][c4 * 4 + 3] = v.w;
    }
    __syncthreads();

    const int tx = tid & 15;        // column lane: cols tx, tx+16, ...
    const int ty = tid >> 4;        // rows ty*4 .. ty*4+3
    constexpr int JC = BN / 16;
    float acc[4][JC];
#pragma unroll
    for (int r = 0; r < 4; ++r)
#pragma unroll
        for (int j = 0; j < JC; ++j) acc[r][j] = 0.f;

    for (int k = 0; k < DIN; ++k) {
        float b[JC];
#pragma unroll
        for (int j = 0; j < JC; ++j) b[j] = Bs[k][tx + j * 16];
#pragma unroll
        for (int r = 0; r < 4; ++r) {
            float a = As[ty * 4 + r][k];
#pragma unroll
            for (int j = 0; j < JC; ++j) acc[r][j] = fmaf(a, b[j], acc[r][j]);
        }
    }

#pragma unroll
    for (int r = 0; r < 4; ++r) {
        int gr = row0 + ty * 4 + r;
        if (gr < N) {
#pragma unroll
            for (int j = 0; j < JC; ++j) Cout[gr * BN + tx + j * 16] = acc[r][j];
        }
    }
}

// ---------------- edge scatter-aggregate (atomics) ----------------
// CC lanes per edge (CC = feature width), 256/CC edges per block.

template<int CC>
__global__ __launch_bounds__(256) void scatter_k(const float* __restrict__ h,
                                                 const int* __restrict__ ei,
                                                 const float* __restrict__ dinv,
                                                 float* __restrict__ agg, int E) {
    constexpr int EPB = 256 / CC;
    int e = blockIdx.x * EPB + (threadIdx.x / CC);
    if (e >= E) return;
    int c = threadIdx.x & (CC - 1);
    int s = ei[e];
    int d = ei[E + e];
    float w = dinv[s] * dinv[d];
    atomicAdd(&agg[d * CC + c], h[s * CC + c] * w);
}

// ---------------- self-loop + bias + relu (layer 1 epilogue) ----------------
// h1[i,c] <- relu(agg1[i,c] + h1[i,c]*dinv[i]^2 + b1[c])

__global__ void sl_bias_relu_k(float* __restrict__ h1, const float* __restrict__ agg1,
                               const float* __restrict__ dinv, const float* __restrict__ b1,
                               int total) {
    int i = blockIdx.x * 256 + threadIdx.x;
    if (i >= total) return;
    int node = i >> 7;              // /128
    int c    = i & 127;
    float sw = dinv[node];
    float v  = agg1[i] + h1[i] * sw * sw + b1[c];
    h1[i] = fmaxf(v, 0.f);
}

// ---------------- layer-2 epilogue: self-loop + bias + log_softmax ----------------
// one wave (64 lanes) per node; out row is N_CLASSES=64 wide.

__global__ __launch_bounds__(256) void finalize_k(float* __restrict__ out,
                                                  const float* __restrict__ h2,
                                                  const float* __restrict__ dinv,
                                                  const float* __restrict__ b2, int N) {
    int node = blockIdx.x * 4 + (threadIdx.x >> 6);
    if (node >= N) return;                      // wave-uniform guard
    int lane = threadIdx.x & 63;
    float sw = dinv[node];
    sw *= sw;
    int idx = node * NCLS + lane;
    float v = out[idx] + h2[idx] * sw + b2[lane];

    float m = v;
#pragma unroll
    for (int off = 32; off > 0; off >>= 1) m = fmaxf(m, __shfl_xor(m, off, 64));
    float s = expf(v - m);
#pragma unroll
    for (int off = 32; off > 0; off >>= 1) s += __shfl_xor(s, off, 64);
    out[idx] = v - m - logf(s);
}

// ---------------- launch ----------------

extern "C" void kernel_launch(void* const* d_in, const int* in_sizes, int n_in,
                              void* d_out, int out_size, void* d_ws, size_t ws_size,
                              hipStream_t stream) {
    const float* x  = (const float*)d_in[0];
    const int*   ei = (const int*)d_in[1];     // [2, E] int32 (src row then dst row)
    const float* W1 = (const float*)d_in[2];
    const float* b1 = (const float*)d_in[3];
    const float* W2 = (const float*)d_in[4];
    const float* b2 = (const float*)d_in[5];
    float* out = (float*)d_out;

    const int N = in_sizes[0] / DIN;
    const int E = in_sizes[1] / 2;

    // workspace: dinv | h1 (N*128) | agg1 (N*128, reused as h2)
    char*  ws   = (char*)d_ws;
    float* dinv = (float*)ws;
    float* h1   = (float*)(ws + ((size_t)(N * 4 + 255) & ~(size_t)255));
    float* agg1 = h1 + (size_t)N * DIN;
    float* h2   = agg1;                         // reuse after layer-1 epilogue

    // degree + normalization
    fill_ones_k<<<(N + 255) / 256, 256, 0, stream>>>(dinv, N);
    deg_count_k<<<(E + 255) / 256, 256, 0, stream>>>(ei, dinv, E);
    rsqrt_k<<<(N + 255) / 256, 256, 0, stream>>>(dinv, N);

    // layer 1
    gemm_k<DIN><<<(N + 63) / 64, 256, 0, stream>>>(x, W1, h1, N);
    hipMemsetAsync(agg1, 0, (size_t)N * DIN * sizeof(float), stream);
    scatter_k<DIN><<<(E + 1) / 2, 256, 0, stream>>>(h1, ei, dinv, agg1, E);
    sl_bias_relu_k<<<(N * DIN + 255) / 256, 256, 0, stream>>>(h1, agg1, dinv, b1, N * DIN);

    // layer 2
    gemm_k<NCLS><<<(N + 63) / 64, 256, 0, stream>>>(h1, W2, h2, N);
    hipMemsetAsync(out, 0, (size_t)N * NCLS * sizeof(float), stream);
    scatter_k<NCLS><<<(E + 3) / 4, 256, 0, stream>>>(h2, ei, dinv, out, E);
    finalize_k<<<(N + 3) / 4, 256, 0, stream>>>(out, h2, dinv, b2, N);
}

// Round 2
// 667.216 us; speedup vs baseline: 2.1353x; 2.1353x over previous
//
#include <hip/hip_runtime.h>
#include <math.h>

#define DIN 128   // D_IN == D_HID == 128
#define NCLS 64

// ---------------- CSR build ----------------

__global__ void hist_k(const int* __restrict__ ei, int* __restrict__ cnt, int E) {
    int e = blockIdx.x * 256 + threadIdx.x;
    if (e < E) atomicAdd(&cnt[ei[E + e]], 1);
}

__global__ void dinv_k(const int* __restrict__ cnt, float* __restrict__ dinv, int N) {
    int i = blockIdx.x * 256 + threadIdx.x;
    if (i < N) dinv[i] = rsqrtf(1.0f + (float)cnt[i]);   // +1 self-loop
}

// exclusive scan of cnt[N] -> off[N], 1024 elems/block
__global__ __launch_bounds__(256) void scan1_k(const int* __restrict__ cnt,
                                               int* __restrict__ off,
                                               int* __restrict__ bsums, int N) {
    __shared__ int tmp[256];
    int base = blockIdx.x * 1024;
    int t = threadIdx.x;
    int loc[4]; int s = 0;
#pragma unroll
    for (int k = 0; k < 4; ++k) {
        int i = base + 4 * t + k;
        int c = (i < N) ? cnt[i] : 0;
        loc[k] = s; s += c;
    }
    tmp[t] = s; __syncthreads();
    for (int o = 1; o < 256; o <<= 1) {
        int x = (t >= o) ? tmp[t - o] : 0;
        __syncthreads();
        tmp[t] += x;
        __syncthreads();
    }
    int excl = (t == 0) ? 0 : tmp[t - 1];
    if (t == 255) bsums[blockIdx.x] = tmp[255];
#pragma unroll
    for (int k = 0; k < 4; ++k) {
        int i = base + 4 * t + k;
        if (i < N) off[i] = excl + loc[k];
    }
}

__global__ __launch_bounds__(256) void scan2_k(int* __restrict__ bs, int nb) {
    __shared__ int tmp[256];
    int t = threadIdx.x;
    int v = (t < nb) ? bs[t] : 0;
    tmp[t] = v; __syncthreads();
    for (int o = 1; o < 256; o <<= 1) {
        int x = (t >= o) ? tmp[t - o] : 0;
        __syncthreads();
        tmp[t] += x;
        __syncthreads();
    }
    int excl = (t == 0) ? 0 : tmp[t - 1];
    if (t < nb) bs[t] = excl;
}

__global__ void scan3_k(int* __restrict__ off, const int* __restrict__ bs, int N, int E) {
    int i = blockIdx.x * 256 + threadIdx.x;
    if (i < N) off[i] += bs[i >> 10];
    if (i == 0) off[N] = E;
}

__global__ void escatter_k(const int* __restrict__ ei, const int* __restrict__ off,
                           int* __restrict__ cursor, int* __restrict__ srcs, int E) {
    int e = blockIdx.x * 256 + threadIdx.x;
    if (e >= E) return;
    int s = ei[e];
    int d = ei[E + e];
    int pos = off[d] + atomicAdd(&cursor[d], 1);
    srcs[pos] = s;
}

// ---------------- tiled fp32 GEMM with row-scale epilogue ----------------
// C[r, :] = dinv[r] * (A[r, :] @ B)

template<int BN>
__global__ __launch_bounds__(256) void gemm_k(const float* __restrict__ A,
                                              const float* __restrict__ B,
                                              const float* __restrict__ dinv,
                                              float* __restrict__ Cout, int N) {
    __shared__ float As[64][DIN + 1];
    __shared__ __align__(16) float Bs[DIN][BN];
    const int tid  = threadIdx.x;
    const int row0 = blockIdx.x * 64;

    {
        const float4* B4  = (const float4*)B;
        float4*       Bs4 = (float4*)&Bs[0][0];
        constexpr int nb4 = DIN * BN / 4;
        for (int i = tid; i < nb4; i += 256) Bs4[i] = B4[i];
    }
    for (int i = tid; i < 64 * (DIN / 4); i += 256) {
        int r  = i >> 5;
        int c4 = i & 31;
        int gr = row0 + r;
        float4 v = make_float4(0.f, 0.f, 0.f, 0.f);
        if (gr < N) v = ((const float4*)A)[gr * (DIN / 4) + c4];
        As[r][c4 * 4 + 0] = v.x;
        As[r][c4 * 4 + 1] = v.y;
        As[r][c4 * 4 + 2] = v.z;
        As[r][c4 * 4 + 3] = v.w;
    }
    __syncthreads();

    const int tx = tid & 15;
    const int ty = tid >> 4;
    constexpr int JC = BN / 16;
    float acc[4][JC];
#pragma unroll
    for (int r = 0; r < 4; ++r)
#pragma unroll
        for (int j = 0; j < JC; ++j) acc[r][j] = 0.f;

    for (int k = 0; k < DIN; ++k) {
        float b[JC];
#pragma unroll
        for (int j = 0; j < JC; ++j) b[j] = Bs[k][tx + j * 16];
#pragma unroll
        for (int r = 0; r < 4; ++r) {
            float a = As[ty * 4 + r][k];
#pragma unroll
            for (int j = 0; j < JC; ++j) acc[r][j] = fmaf(a, b[j], acc[r][j]);
        }
    }

#pragma unroll
    for (int r = 0; r < 4; ++r) {
        int gr = row0 + ty * 4 + r;
        if (gr < N) {
            float sc = dinv[gr];
#pragma unroll
            for (int j = 0; j < JC; ++j) Cout[gr * BN + tx + j * 16] = acc[r][j] * sc;
        }
    }
}

// ---------------- gather layer 1: one wave per node, 128 cols (float2/lane) ----------------
// h1p[d] = relu(dinv[d] * (sum_{e: dst=d} hs[src] + hs[d]) + b1)

__global__ __launch_bounds__(256) void gather1_k(const float* __restrict__ hs,
                                                 const int* __restrict__ off,
                                                 const int* __restrict__ srcs,
                                                 const float* __restrict__ dinv,
                                                 const float* __restrict__ b1,
                                                 float* __restrict__ outp, int N) {
    int node = blockIdx.x * 4 + (threadIdx.x >> 6);
    if (node >= N) return;
    int lane = threadIdx.x & 63;
    int beg = off[node], end = off[node + 1];
    const float2* hp = (const float2*)hs;
    float ax = 0.f, ay = 0.f;
    int j = beg;
    for (; j + 1 < end; j += 2) {
        int s0 = srcs[j], s1 = srcs[j + 1];
        float2 v0 = hp[s0 * 64 + lane];
        float2 v1 = hp[s1 * 64 + lane];
        ax += v0.x + v1.x;
        ay += v0.y + v1.y;
    }
    if (j < end) {
        float2 v = hp[srcs[j] * 64 + lane];
        ax += v.x; ay += v.y;
    }
    float2 self = hp[node * 64 + lane];
    ax += self.x; ay += self.y;
    float d = dinv[node];
    float2 b = ((const float2*)b1)[lane];
    float2 o;
    o.x = fmaxf(fmaf(d, ax, b.x), 0.f);
    o.y = fmaxf(fmaf(d, ay, b.y), 0.f);
    ((float2*)outp)[node * 64 + lane] = o;
}

// ---------------- gather layer 2 + log_softmax: one wave per node, 64 cols ----------------

__global__ __launch_bounds__(256) void gather2_k(const float* __restrict__ hs,
                                                 const int* __restrict__ off,
                                                 const int* __restrict__ srcs,
                                                 const float* __restrict__ dinv,
                                                 const float* __restrict__ b2,
                                                 float* __restrict__ out, int N) {
    int node = blockIdx.x * 4 + (threadIdx.x >> 6);
    if (node >= N) return;
    int lane = threadIdx.x & 63;
    int beg = off[node], end = off[node + 1];
    float acc = 0.f;
    int j = beg;
    for (; j + 1 < end; j += 2) {
        float v0 = hs[srcs[j] * NCLS + lane];
        float v1 = hs[srcs[j + 1] * NCLS + lane];
        acc += v0 + v1;
    }
    if (j < end) acc += hs[srcs[j] * NCLS + lane];
    acc += hs[node * NCLS + lane];
    float v = fmaf(dinv[node], acc, b2[lane]);

    float m = v;
#pragma unroll
    for (int o = 32; o > 0; o >>= 1) m = fmaxf(m, __shfl_xor(m, o, 64));
    float s = expf(v - m);
#pragma unroll
    for (int o = 32; o > 0; o >>= 1) s += __shfl_xor(s, o, 64);
    out[node * NCLS + lane] = v - m - logf(s);
}

// ---------------- launch ----------------

extern "C" void kernel_launch(void* const* d_in, const int* in_sizes, int n_in,
                              void* d_out, int out_size, void* d_ws, size_t ws_size,
                              hipStream_t stream) {
    const float* x  = (const float*)d_in[0];
    const int*   ei = (const int*)d_in[1];
    const float* W1 = (const float*)d_in[2];
    const float* b1 = (const float*)d_in[3];
    const float* W2 = (const float*)d_in[4];
    const float* b2 = (const float*)d_in[5];
    float* out = (float*)d_out;

    const int N = in_sizes[0] / DIN;
    const int E = in_sizes[1] / 2;

    char* p = (char*)d_ws;
    auto alloc = [&](size_t bytes) { void* r = p; p += (bytes + 255) & ~(size_t)255; return r; };
    float* dinv  = (float*)alloc((size_t)N * 4);
    int*   cnt   = (int*)  alloc((size_t)N * 4);     // reused as cursor
    int*   off   = (int*)  alloc((size_t)(N + 1) * 4);
    int*   bsums = (int*)  alloc(1024);
    int*   srcs  = (int*)  alloc((size_t)E * 4);
    float* b0    = (float*)alloc((size_t)N * DIN * 4);  // hs1, then hs2
    float* bufB  = (float*)alloc((size_t)N * DIN * 4);  // h1p

    const int nb = (N + 1023) / 1024;

    // CSR build + normalization
    hipMemsetAsync(cnt, 0, (size_t)N * 4, stream);
    hist_k<<<(E + 255) / 256, 256, 0, stream>>>(ei, cnt, E);
    dinv_k<<<(N + 255) / 256, 256, 0, stream>>>(cnt, dinv, N);
    scan1_k<<<nb, 256, 0, stream>>>(cnt, off, bsums, N);
    scan2_k<<<1, 256, 0, stream>>>(bsums, nb);
    scan3_k<<<(N + 255) / 256, 256, 0, stream>>>(off, bsums, N, E);
    hipMemsetAsync(cnt, 0, (size_t)N * 4, stream);      // cursor
    escatter_k<<<(E + 255) / 256, 256, 0, stream>>>(ei, off, cnt, srcs, E);

    // layer 1
    gemm_k<DIN><<<(N + 63) / 64, 256, 0, stream>>>(x, W1, dinv, b0, N);
    gather1_k<<<(N + 3) / 4, 256, 0, stream>>>(b0, off, srcs, dinv, b1, bufB, N);

    // layer 2
    gemm_k<NCLS><<<(N + 63) / 64, 256, 0, stream>>>(bufB, W2, dinv, b0, N);
    gather2_k<<<(N + 3) / 4, 256, 0, stream>>>(b0, off, srcs, dinv, b2, out, N);
}

// Round 3
// 440.882 us; speedup vs baseline: 3.2316x; 1.5134x over previous
//
#include <hip/hip_runtime.h>
#include <math.h>

#define DIN 128   // D_IN == D_HID == 128
#define NCLS 64

typedef __attribute__((ext_vector_type(4))) float  f32x4;
typedef __attribute__((ext_vector_type(8))) short  bf16x8;   // MFMA A/B frag (4 VGPRs)

__device__ inline unsigned short f2bf(float f) {             // round-to-nearest-even
    unsigned int u = __float_as_uint(f);
    u += 0x7fff + ((u >> 16) & 1);
    return (unsigned short)(u >> 16);
}
__device__ inline float bf2f(unsigned int hi) { return __uint_as_float(hi << 16); }

// ---------------- CSR build ----------------

__global__ void hist_k(const int* __restrict__ ei, int* __restrict__ cnt, int E) {
    int e = blockIdx.x * 256 + threadIdx.x;
    if (e < E) atomicAdd(&cnt[ei[E + e]], 1);
}

__global__ void dinv_k(const int* __restrict__ cnt, float* __restrict__ dinv, int N) {
    int i = blockIdx.x * 256 + threadIdx.x;
    if (i < N) dinv[i] = rsqrtf(1.0f + (float)cnt[i]);   // +1 self-loop
}

__global__ __launch_bounds__(256) void scan1_k(const int* __restrict__ cnt,
                                               int* __restrict__ off,
                                               int* __restrict__ bsums, int N) {
    __shared__ int tmp[256];
    int base = blockIdx.x * 1024;
    int t = threadIdx.x;
    int loc[4]; int s = 0;
#pragma unroll
    for (int k = 0; k < 4; ++k) {
        int i = base + 4 * t + k;
        int c = (i < N) ? cnt[i] : 0;
        loc[k] = s; s += c;
    }
    tmp[t] = s; __syncthreads();
    for (int o = 1; o < 256; o <<= 1) {
        int x = (t >= o) ? tmp[t - o] : 0;
        __syncthreads();
        tmp[t] += x;
        __syncthreads();
    }
    int excl = (t == 0) ? 0 : tmp[t - 1];
    if (t == 255) bsums[blockIdx.x] = tmp[255];
#pragma unroll
    for (int k = 0; k < 4; ++k) {
        int i = base + 4 * t + k;
        if (i < N) off[i] = excl + loc[k];
    }
}

__global__ __launch_bounds__(256) void scan2_k(int* __restrict__ bs, int nb) {
    __shared__ int tmp[256];
    int t = threadIdx.x;
    int v = (t < nb) ? bs[t] : 0;
    tmp[t] = v; __syncthreads();
    for (int o = 1; o < 256; o <<= 1) {
        int x = (t >= o) ? tmp[t - o] : 0;
        __syncthreads();
        tmp[t] += x;
        __syncthreads();
    }
    int excl = (t == 0) ? 0 : tmp[t - 1];
    if (t < nb) bs[t] = excl;
}

__global__ void scan3_k(int* __restrict__ off, const int* __restrict__ bs, int N, int E) {
    int i = blockIdx.x * 256 + threadIdx.x;
    if (i < N) off[i] += bs[i >> 10];
    if (i == 0) off[N] = E;
}

__global__ void escatter_k(const int* __restrict__ ei, const int* __restrict__ off,
                           int* __restrict__ cursor, int* __restrict__ srcs, int E) {
    int e = blockIdx.x * 256 + threadIdx.x;
    if (e >= E) return;
    int s = ei[e];
    int d = ei[E + e];
    int pos = off[d] + atomicAdd(&cursor[d], 1);
    srcs[pos] = s;
}

// ---------------- W prep: transpose + cast to bf16 ----------------
// wt1[n][k] = bf16(W1[k][n]) (128x128), wt2[n][k] = bf16(W2[k][n]) (64x128)

__global__ void wprep_k(const float* __restrict__ W1, const float* __restrict__ W2,
                        unsigned short* __restrict__ wt1, unsigned short* __restrict__ wt2) {
    int i = blockIdx.x * 256 + threadIdx.x;
    if (i < 128 * 128) { int k = i >> 7, n = i & 127; wt1[n * 128 + k] = f2bf(W1[i]); }
    if (i < 128 * 64)  { int k = i >> 6, n = i & 63;  wt2[n * 128 + k] = f2bf(W2[i]); }
}

// ---------------- MFMA bf16 GEMM: C[r,:] = bf16(dinv[r] * (A[r,:] @ B)) ----------------
// block = 256 thr (4 waves), 128 rows x BN cols per block, K=128 staged fully in LDS.
// A source is fp32 (AFP32) or bf16. Bt is pre-transposed bf16 [BN][128].

template<int BN, bool AFP32>
__global__ __launch_bounds__(256) void mgemm_k(const void* __restrict__ Ap,
                                               const unsigned short* __restrict__ Bt,
                                               const float* __restrict__ dinv,
                                               unsigned short* __restrict__ C,
                                               int N) {
    constexpr int LDK = DIN + 8;                 // pad: frag reads -> 2-way max (free)
    __shared__ unsigned short As[128 * LDK];
    __shared__ unsigned short Bs[BN * LDK];
    const int tid  = threadIdx.x;
    const int row0 = blockIdx.x * 128;

    // stage B (BN x 128 bf16), 16B chunks
    for (int idx = tid; idx < BN * 16; idx += 256) {
        int n = idx >> 4, c = (idx & 15) << 3;
        *(uint4*)&Bs[n * LDK + c] = *(const uint4*)&Bt[n * DIN + c];
    }
    // stage A (128 x 128), cast fp32->bf16 on the fly if needed
    for (int idx = tid; idx < 128 * 16; idx += 256) {
        int r = idx >> 4, c = (idx & 15) << 3;
        int gr = row0 + r;
        if (AFP32) {
            unsigned short v[8];
            if (gr < N) {
                const float* A = (const float*)Ap;
                f32x4 a0 = *(const f32x4*)&A[(size_t)gr * DIN + c];
                f32x4 a1 = *(const f32x4*)&A[(size_t)gr * DIN + c + 4];
                v[0] = f2bf(a0.x); v[1] = f2bf(a0.y); v[2] = f2bf(a0.z); v[3] = f2bf(a0.w);
                v[4] = f2bf(a1.x); v[5] = f2bf(a1.y); v[6] = f2bf(a1.z); v[7] = f2bf(a1.w);
            } else {
#pragma unroll
                for (int j = 0; j < 8; ++j) v[j] = 0;
            }
            *(uint4*)&As[r * LDK + c] = *(const uint4*)v;
        } else {
            uint4 v = make_uint4(0, 0, 0, 0);
            if (gr < N) v = *(const uint4*)&((const unsigned short*)Ap)[(size_t)gr * DIN + c];
            *(uint4*)&As[r * LDK + c] = v;
        }
    }
    __syncthreads();

    const int wave = tid >> 6, lane = tid & 63;
    const int lrow = lane & 15, kq = lane >> 4;
    constexpr int NT = BN / 16;
    f32x4 acc[2][NT];
#pragma unroll
    for (int m = 0; m < 2; ++m)
#pragma unroll
        for (int t = 0; t < NT; ++t) acc[m][t] = (f32x4){0.f, 0.f, 0.f, 0.f};

    const unsigned short* Abase = &As[(wave * 32 + lrow) * LDK + kq * 8];
    const unsigned short* Bbase = &Bs[lrow * LDK + kq * 8];
#pragma unroll
    for (int kk = 0; kk < 4; ++kk) {                   // K = 4 x 32
        bf16x8 a0 = *(const bf16x8*)(Abase + kk * 32);
        bf16x8 a1 = *(const bf16x8*)(Abase + 16 * LDK + kk * 32);
        bf16x8 bfr[NT];
#pragma unroll
        for (int t = 0; t < NT; ++t)
            bfr[t] = *(const bf16x8*)(Bbase + t * 16 * LDK + kk * 32);
#pragma unroll
        for (int t = 0; t < NT; ++t) {
            acc[0][t] = __builtin_amdgcn_mfma_f32_16x16x32_bf16(a0, bfr[t], acc[0][t], 0, 0, 0);
            acc[1][t] = __builtin_amdgcn_mfma_f32_16x16x32_bf16(a1, bfr[t], acc[1][t], 0, 0, 0);
        }
    }

    // epilogue: C/D layout col=lane&15, row=(lane>>4)*4+reg
#pragma unroll
    for (int tm = 0; tm < 2; ++tm) {
        int rb = row0 + wave * 32 + tm * 16 + kq * 4;
#pragma unroll
        for (int r = 0; r < 4; ++r) {
            int gr = rb + r;
            if (gr < N) {
                float sc = dinv[gr];
#pragma unroll
                for (int t = 0; t < NT; ++t)
                    C[(size_t)gr * BN + t * 16 + lrow] = f2bf(acc[tm][t][r] * sc);
            }
        }
    }
}

// ---------------- gather layer 1 (bf16 in/out): one wave per node, bf16x2 per lane ----------------

__global__ __launch_bounds__(256) void gather1_k(const unsigned short* __restrict__ hs,
                                                 const int* __restrict__ off,
                                                 const int* __restrict__ srcs,
                                                 const float* __restrict__ dinv,
                                                 const float* __restrict__ b1,
                                                 unsigned short* __restrict__ outp, int N) {
    int node = blockIdx.x * 4 + (threadIdx.x >> 6);
    if (node >= N) return;
    int lane = threadIdx.x & 63;
    int beg = off[node], end = off[node + 1];
    const unsigned int* hp = (const unsigned int*)hs;   // [N][64] bf16x2
    float ax = 0.f, ay = 0.f;
    int j = beg;
    for (; j + 3 < end; j += 4) {
        unsigned int v0 = hp[(size_t)srcs[j]     * 64 + lane];
        unsigned int v1 = hp[(size_t)srcs[j + 1] * 64 + lane];
        unsigned int v2 = hp[(size_t)srcs[j + 2] * 64 + lane];
        unsigned int v3 = hp[(size_t)srcs[j + 3] * 64 + lane];
        ax += bf2f(v0 & 0xffff) + bf2f(v1 & 0xffff) + bf2f(v2 & 0xffff) + bf2f(v3 & 0xffff);
        ay += bf2f(v0 >> 16) + bf2f(v1 >> 16) + bf2f(v2 >> 16) + bf2f(v3 >> 16);
    }
    for (; j < end; ++j) {
        unsigned int v = hp[(size_t)srcs[j] * 64 + lane];
        ax += bf2f(v & 0xffff); ay += bf2f(v >> 16);
    }
    unsigned int sv = hp[(size_t)node * 64 + lane];
    ax += bf2f(sv & 0xffff); ay += bf2f(sv >> 16);
    float d = dinv[node];
    float2 b = ((const float2*)b1)[lane];
    float ox = fmaxf(fmaf(d, ax, b.x), 0.f);
    float oy = fmaxf(fmaf(d, ay, b.y), 0.f);
    ((unsigned int*)outp)[(size_t)node * 64 + lane] = (unsigned int)f2bf(ox) | ((unsigned int)f2bf(oy) << 16);
}

// ---------------- gather layer 2 + log_softmax: 2 nodes per wave (32 lanes each) ----------------

__global__ __launch_bounds__(256) void gather2_k(const unsigned short* __restrict__ hs,
                                                 const int* __restrict__ off,
                                                 const int* __restrict__ srcs,
                                                 const float* __restrict__ dinv,
                                                 const float* __restrict__ b2,
                                                 float* __restrict__ out, int N) {
    int node = blockIdx.x * 8 + (threadIdx.x >> 5);
    if (node >= N) return;
    int sl = threadIdx.x & 31;
    int beg = off[node], end = off[node + 1];
    const unsigned int* hp = (const unsigned int*)hs;   // [N][32] bf16x2
    float ax = 0.f, ay = 0.f;
    int j = beg;
    for (; j + 3 < end; j += 4) {
        unsigned int v0 = hp[(size_t)srcs[j]     * 32 + sl];
        unsigned int v1 = hp[(size_t)srcs[j + 1] * 32 + sl];
        unsigned int v2 = hp[(size_t)srcs[j + 2] * 32 + sl];
        unsigned int v3 = hp[(size_t)srcs[j + 3] * 32 + sl];
        ax += bf2f(v0 & 0xffff) + bf2f(v1 & 0xffff) + bf2f(v2 & 0xffff) + bf2f(v3 & 0xffff);
        ay += bf2f(v0 >> 16) + bf2f(v1 >> 16) + bf2f(v2 >> 16) + bf2f(v3 >> 16);
    }
    for (; j < end; ++j) {
        unsigned int v = hp[(size_t)srcs[j] * 32 + sl];
        ax += bf2f(v & 0xffff); ay += bf2f(v >> 16);
    }
    unsigned int sv = hp[(size_t)node * 32 + sl];
    ax += bf2f(sv & 0xffff); ay += bf2f(sv >> 16);
    float d = dinv[node];
    float2 b = ((const float2*)b2)[sl];
    float vx = fmaf(d, ax, b.x);
    float vy = fmaf(d, ay, b.y);

    float m = fmaxf(vx, vy);
#pragma unroll
    for (int o = 16; o > 0; o >>= 1) m = fmaxf(m, __shfl_xor(m, o, 32));
    float s = expf(vx - m) + expf(vy - m);
#pragma unroll
    for (int o = 16; o > 0; o >>= 1) s += __shfl_xor(s, o, 32);
    float ls = logf(s);
    float2 o2; o2.x = vx - m - ls; o2.y = vy - m - ls;
    ((float2*)out)[(size_t)node * 32 + sl] = o2;
}

// ---------------- launch ----------------

extern "C" void kernel_launch(void* const* d_in, const int* in_sizes, int n_in,
                              void* d_out, int out_size, void* d_ws, size_t ws_size,
                              hipStream_t stream) {
    const float* x  = (const float*)d_in[0];
    const int*   ei = (const int*)d_in[1];
    const float* W1 = (const float*)d_in[2];
    const float* b1 = (const float*)d_in[3];
    const float* W2 = (const float*)d_in[4];
    const float* b2 = (const float*)d_in[5];
    float* out = (float*)d_out;

    const int N = in_sizes[0] / DIN;
    const int E = in_sizes[1] / 2;

    char* p = (char*)d_ws;
    auto alloc = [&](size_t bytes) { void* r = p; p += (bytes + 255) & ~(size_t)255; return r; };
    float* dinv  = (float*)alloc((size_t)N * 4);
    int*   cnt   = (int*)  alloc((size_t)N * 4);     // reused as cursor
    int*   off   = (int*)  alloc((size_t)(N + 1) * 4);
    int*   bsums = (int*)  alloc(1024);
    int*   srcs  = (int*)  alloc((size_t)E * 4);
    unsigned short* wt1 = (unsigned short*)alloc(128 * 128 * 2);
    unsigned short* wt2 = (unsigned short*)alloc(64 * 128 * 2);
    unsigned short* hs1 = (unsigned short*)alloc((size_t)N * DIN * 2);
    unsigned short* h1p = (unsigned short*)alloc((size_t)N * DIN * 2);
    unsigned short* hs2 = (unsigned short*)alloc((size_t)N * NCLS * 2);

    const int nb = (N + 1023) / 1024;

    // W prep + CSR build + normalization
    wprep_k<<<64, 256, 0, stream>>>(W1, W2, wt1, wt2);
    hipMemsetAsync(cnt, 0, (size_t)N * 4, stream);
    hist_k<<<(E + 255) / 256, 256, 0, stream>>>(ei, cnt, E);
    dinv_k<<<(N + 255) / 256, 256, 0, stream>>>(cnt, dinv, N);
    scan1_k<<<nb, 256, 0, stream>>>(cnt, off, bsums, N);
    scan2_k<<<1, 256, 0, stream>>>(bsums, nb);
    scan3_k<<<(N + 255) / 256, 256, 0, stream>>>(off, bsums, N, E);
    hipMemsetAsync(cnt, 0, (size_t)N * 4, stream);
    escatter_k<<<(E + 255) / 256, 256, 0, stream>>>(ei, off, cnt, srcs, E);

    // layer 1
    mgemm_k<DIN, true><<<(N + 127) / 128, 256, 0, stream>>>(x, wt1, dinv, hs1, N);
    gather1_k<<<(N + 3) / 4, 256, 0, stream>>>(hs1, off, srcs, dinv, b1, h1p, N);

    // layer 2
    mgemm_k<NCLS, false><<<(N + 127) / 128, 256, 0, stream>>>(h1p, wt2, dinv, hs2, N);
    gather2_k<<<(N + 7) / 8, 256, 0, stream>>>(hs2, off, srcs, dinv, b2, out, N);
}

// Round 4
// 298.870 us; speedup vs baseline: 4.7671x; 1.4752x over previous
//
#include <hip/hip_runtime.h>
#include <math.h>

#define DIN 128   // D_IN == D_HID == 128
#define NCLS 64
#define BCAP 5120 // per-bucket capacity: mean 4096, sd 64 -> +16 sigma

typedef __attribute__((ext_vector_type(4))) float  f32x4;
typedef __attribute__((ext_vector_type(8))) short  bf16x8;   // MFMA A/B frag (4 VGPRs)

__device__ inline unsigned short f2bf(float f) {             // round-to-nearest-even
    unsigned int u = __float_as_uint(f);
    u += 0x7fff + ((u >> 16) & 1);
    return (unsigned short)(u >> 16);
}
__device__ inline float bf2f(unsigned int hi) { return __uint_as_float(hi << 16); }

// ---------------- CSR build: bucketed two-phase counting sort ----------------
// bucket = dst >> 8 (256 nodes per bucket). Pass A bins edges into padded
// bucket regions; pass B counting-sorts each bucket by dst&255, emitting
// final CSR (off, srcs) + dinv with coalesced writes.

__global__ __launch_bounds__(256) void binA_k(const int* __restrict__ ei,
                                              int* __restrict__ gcnt,
                                              unsigned int* __restrict__ tmp,
                                              int E, int NB) {
    __shared__ int lcnt[512];
    __shared__ int gpos[512];
    const int t = threadIdx.x;
    for (int i = t; i < NB; i += 256) lcnt[i] = 0;
    __syncthreads();

    const int base = blockIdx.x * 4096;
    unsigned int pk[16];
    short bk[16], rk[16];
#pragma unroll
    for (int k = 0; k < 16; ++k) {
        int e = base + k * 256 + t;
        if (e < E) {
            int s = ei[e];
            int d = ei[E + e];
            int b = d >> 8;
            pk[k] = ((unsigned int)s << 8) | (unsigned int)(d & 255);
            bk[k] = (short)b;
            rk[k] = (short)atomicAdd(&lcnt[b], 1);
        } else {
            bk[k] = -1;
        }
    }
    __syncthreads();
    for (int i = t; i < NB; i += 256)
        gpos[i] = lcnt[i] ? atomicAdd(&gcnt[i], lcnt[i]) : 0;
    __syncthreads();
#pragma unroll
    for (int k = 0; k < 16; ++k) {
        if (bk[k] >= 0) {
            int b = bk[k];
            int pos = gpos[b] + rk[k];
            if (pos < BCAP) tmp[(size_t)b * BCAP + pos] = pk[k];
        }
    }
}

// exclusive scan of gcnt[NB] -> bbase[NB]; launch 1 block x 512 threads
__global__ __launch_bounds__(512) void scanb_k(const int* __restrict__ gcnt,
                                               int* __restrict__ bbase, int NB) {
    __shared__ int tmp[512];
    int t = threadIdx.x;
    int v = (t < NB) ? gcnt[t] : 0;
    tmp[t] = v; __syncthreads();
    for (int o = 1; o < 512; o <<= 1) {
        int x = (t >= o) ? tmp[t - o] : 0;
        __syncthreads();
        tmp[t] += x;
        __syncthreads();
    }
    if (t < NB) bbase[t] = (t == 0) ? 0 : tmp[t - 1];
}

// one block per bucket: counting sort by dst&255, emit CSR + dinv
__global__ __launch_bounds__(256) void binB_k(const unsigned int* __restrict__ tmp,
                                              const int* __restrict__ gcnt,
                                              const int* __restrict__ bbase,
                                              int* __restrict__ off,
                                              float* __restrict__ dinv,
                                              int* __restrict__ srcs,
                                              int N, int E) {
    __shared__ unsigned int stg[BCAP];
    __shared__ int lcnt[256], sc[256], loff[256], lcur[256];
    const int b = blockIdx.x, t = threadIdx.x;
    int cnt = gcnt[b];
    if (cnt > BCAP) cnt = BCAP;
    const int base = bbase[b];
    lcnt[t] = 0; lcur[t] = 0;
    __syncthreads();
    for (int i = t; i < cnt; i += 256) {
        unsigned int v = tmp[(size_t)b * BCAP + i];
        stg[i] = v;
        atomicAdd(&lcnt[v & 255u], 1);
    }
    __syncthreads();
    // exclusive scan of lcnt -> loff
    sc[t] = lcnt[t]; __syncthreads();
    for (int o = 1; o < 256; o <<= 1) {
        int x = (t >= o) ? sc[t - o] : 0;
        __syncthreads();
        sc[t] += x;
        __syncthreads();
    }
    int excl = (t == 0) ? 0 : sc[t - 1];
    loff[t] = excl;
    int node = b * 256 + t;
    if (node <= N) off[node] = base + excl;          // off[N] = E falls out naturally
    if (node < N)  dinv[node] = rsqrtf(1.0f + (float)lcnt[t]);
    __syncthreads();
    for (int i = t; i < cnt; i += 256) {
        unsigned int v = stg[i];
        int l = v & 255u;
        int r = atomicAdd(&lcur[l], 1);
        srcs[base + loff[l] + r] = (int)(v >> 8);
    }
}

// ---------------- W prep: transpose + cast to bf16 ----------------

__global__ void wprep_k(const float* __restrict__ W1, const float* __restrict__ W2,
                        unsigned short* __restrict__ wt1, unsigned short* __restrict__ wt2) {
    int i = blockIdx.x * 256 + threadIdx.x;
    if (i < 128 * 128) { int k = i >> 7, n = i & 127; wt1[n * 128 + k] = f2bf(W1[i]); }
    if (i < 128 * 64)  { int k = i >> 6, n = i & 63;  wt2[n * 128 + k] = f2bf(W2[i]); }
}

// ---------------- MFMA bf16 GEMM: C[r,:] = bf16(dinv[r] * (A[r,:] @ B)) ----------------

template<int BN, bool AFP32>
__global__ __launch_bounds__(256) void mgemm_k(const void* __restrict__ Ap,
                                               const unsigned short* __restrict__ Bt,
                                               const float* __restrict__ dinv,
                                               unsigned short* __restrict__ C,
                                               int N) {
    constexpr int LDK = DIN + 8;
    __shared__ unsigned short As[128 * LDK];
    __shared__ unsigned short Bs[BN * LDK];
    const int tid  = threadIdx.x;
    const int row0 = blockIdx.x * 128;

    for (int idx = tid; idx < BN * 16; idx += 256) {
        int n = idx >> 4, c = (idx & 15) << 3;
        *(uint4*)&Bs[n * LDK + c] = *(const uint4*)&Bt[n * DIN + c];
    }
    for (int idx = tid; idx < 128 * 16; idx += 256) {
        int r = idx >> 4, c = (idx & 15) << 3;
        int gr = row0 + r;
        if (AFP32) {
            unsigned short v[8];
            if (gr < N) {
                const float* A = (const float*)Ap;
                f32x4 a0 = *(const f32x4*)&A[(size_t)gr * DIN + c];
                f32x4 a1 = *(const f32x4*)&A[(size_t)gr * DIN + c + 4];
                v[0] = f2bf(a0.x); v[1] = f2bf(a0.y); v[2] = f2bf(a0.z); v[3] = f2bf(a0.w);
                v[4] = f2bf(a1.x); v[5] = f2bf(a1.y); v[6] = f2bf(a1.z); v[7] = f2bf(a1.w);
            } else {
#pragma unroll
                for (int j = 0; j < 8; ++j) v[j] = 0;
            }
            *(uint4*)&As[r * LDK + c] = *(const uint4*)v;
        } else {
            uint4 v = make_uint4(0, 0, 0, 0);
            if (gr < N) v = *(const uint4*)&((const unsigned short*)Ap)[(size_t)gr * DIN + c];
            *(uint4*)&As[r * LDK + c] = v;
        }
    }
    __syncthreads();

    const int wave = tid >> 6, lane = tid & 63;
    const int lrow = lane & 15, kq = lane >> 4;
    constexpr int NT = BN / 16;
    f32x4 acc[2][NT];
#pragma unroll
    for (int m = 0; m < 2; ++m)
#pragma unroll
        for (int t = 0; t < NT; ++t) acc[m][t] = (f32x4){0.f, 0.f, 0.f, 0.f};

    const unsigned short* Abase = &As[(wave * 32 + lrow) * LDK + kq * 8];
    const unsigned short* Bbase = &Bs[lrow * LDK + kq * 8];
#pragma unroll
    for (int kk = 0; kk < 4; ++kk) {
        bf16x8 a0 = *(const bf16x8*)(Abase + kk * 32);
        bf16x8 a1 = *(const bf16x8*)(Abase + 16 * LDK + kk * 32);
        bf16x8 bfr[NT];
#pragma unroll
        for (int t = 0; t < NT; ++t)
            bfr[t] = *(const bf16x8*)(Bbase + t * 16 * LDK + kk * 32);
#pragma unroll
        for (int t = 0; t < NT; ++t) {
            acc[0][t] = __builtin_amdgcn_mfma_f32_16x16x32_bf16(a0, bfr[t], acc[0][t], 0, 0, 0);
            acc[1][t] = __builtin_amdgcn_mfma_f32_16x16x32_bf16(a1, bfr[t], acc[1][t], 0, 0, 0);
        }
    }

#pragma unroll
    for (int tm = 0; tm < 2; ++tm) {
        int rb = row0 + wave * 32 + tm * 16 + kq * 4;
#pragma unroll
        for (int r = 0; r < 4; ++r) {
            int gr = rb + r;
            if (gr < N) {
                float sc2 = dinv[gr];
#pragma unroll
                for (int t = 0; t < NT; ++t)
                    C[(size_t)gr * BN + t * 16 + lrow] = f2bf(acc[tm][t][r] * sc2);
            }
        }
    }
}

// ---------------- gather layer 1 (bf16 in/out): one wave per node ----------------

__global__ __launch_bounds__(256) void gather1_k(const unsigned short* __restrict__ hs,
                                                 const int* __restrict__ off,
                                                 const int* __restrict__ srcs,
                                                 const float* __restrict__ dinv,
                                                 const float* __restrict__ b1,
                                                 unsigned short* __restrict__ outp, int N) {
    int node = blockIdx.x * 4 + (threadIdx.x >> 6);
    if (node >= N) return;
    int lane = threadIdx.x & 63;
    int beg = off[node], end = off[node + 1];
    const unsigned int* hp = (const unsigned int*)hs;   // [N][64] bf16x2
    float ax = 0.f, ay = 0.f;
    int j = beg;
    for (; j + 3 < end; j += 4) {
        unsigned int v0 = hp[(size_t)srcs[j]     * 64 + lane];
        unsigned int v1 = hp[(size_t)srcs[j + 1] * 64 + lane];
        unsigned int v2 = hp[(size_t)srcs[j + 2] * 64 + lane];
        unsigned int v3 = hp[(size_t)srcs[j + 3] * 64 + lane];
        ax += bf2f(v0 & 0xffff) + bf2f(v1 & 0xffff) + bf2f(v2 & 0xffff) + bf2f(v3 & 0xffff);
        ay += bf2f(v0 >> 16) + bf2f(v1 >> 16) + bf2f(v2 >> 16) + bf2f(v3 >> 16);
    }
    for (; j < end; ++j) {
        unsigned int v = hp[(size_t)srcs[j] * 64 + lane];
        ax += bf2f(v & 0xffff); ay += bf2f(v >> 16);
    }
    unsigned int sv = hp[(size_t)node * 64 + lane];
    ax += bf2f(sv & 0xffff); ay += bf2f(sv >> 16);
    float d = dinv[node];
    float2 b = ((const float2*)b1)[lane];
    float ox = fmaxf(fmaf(d, ax, b.x), 0.f);
    float oy = fmaxf(fmaf(d, ay, b.y), 0.f);
    ((unsigned int*)outp)[(size_t)node * 64 + lane] = (unsigned int)f2bf(ox) | ((unsigned int)f2bf(oy) << 16);
}

// ---------------- gather layer 2 + log_softmax: 2 nodes per wave ----------------

__global__ __launch_bounds__(256) void gather2_k(const unsigned short* __restrict__ hs,
                                                 const int* __restrict__ off,
                                                 const int* __restrict__ srcs,
                                                 const float* __restrict__ dinv,
                                                 const float* __restrict__ b2,
                                                 float* __restrict__ out, int N) {
    int node = blockIdx.x * 8 + (threadIdx.x >> 5);
    if (node >= N) return;
    int sl = threadIdx.x & 31;
    int beg = off[node], end = off[node + 1];
    const unsigned int* hp = (const unsigned int*)hs;   // [N][32] bf16x2
    float ax = 0.f, ay = 0.f;
    int j = beg;
    for (; j + 3 < end; j += 4) {
        unsigned int v0 = hp[(size_t)srcs[j]     * 32 + sl];
        unsigned int v1 = hp[(size_t)srcs[j + 1] * 32 + sl];
        unsigned int v2 = hp[(size_t)srcs[j + 2] * 32 + sl];
        unsigned int v3 = hp[(size_t)srcs[j + 3] * 32 + sl];
        ax += bf2f(v0 & 0xffff) + bf2f(v1 & 0xffff) + bf2f(v2 & 0xffff) + bf2f(v3 & 0xffff);
        ay += bf2f(v0 >> 16) + bf2f(v1 >> 16) + bf2f(v2 >> 16) + bf2f(v3 >> 16);
    }
    for (; j < end; ++j) {
        unsigned int v = hp[(size_t)srcs[j] * 32 + sl];
        ax += bf2f(v & 0xffff); ay += bf2f(v >> 16);
    }
    unsigned int sv = hp[(size_t)node * 32 + sl];
    ax += bf2f(sv & 0xffff); ay += bf2f(sv >> 16);
    float d = dinv[node];
    float2 b = ((const float2*)b2)[sl];
    float vx = fmaf(d, ax, b.x);
    float vy = fmaf(d, ay, b.y);

    float m = fmaxf(vx, vy);
#pragma unroll
    for (int o = 16; o > 0; o >>= 1) m = fmaxf(m, __shfl_xor(m, o, 32));
    float s = expf(vx - m) + expf(vy - m);
#pragma unroll
    for (int o = 16; o > 0; o >>= 1) s += __shfl_xor(s, o, 32);
    float ls = logf(s);
    float2 o2; o2.x = vx - m - ls; o2.y = vy - m - ls;
    ((float2*)out)[(size_t)node * 32 + sl] = o2;
}

// ---------------- launch ----------------

extern "C" void kernel_launch(void* const* d_in, const int* in_sizes, int n_in,
                              void* d_out, int out_size, void* d_ws, size_t ws_size,
                              hipStream_t stream) {
    const float* x  = (const float*)d_in[0];
    const int*   ei = (const int*)d_in[1];
    const float* W1 = (const float*)d_in[2];
    const float* b1 = (const float*)d_in[3];
    const float* W2 = (const float*)d_in[4];
    const float* b2 = (const float*)d_in[5];
    float* out = (float*)d_out;

    const int N  = in_sizes[0] / DIN;
    const int E  = in_sizes[1] / 2;
    const int NB = (N + 255) >> 8;               // buckets of 256 nodes

    char* p = (char*)d_ws;
    auto alloc = [&](size_t bytes) { void* r = p; p += (bytes + 255) & ~(size_t)255; return r; };
    float* dinv  = (float*)alloc((size_t)N * 4);
    int*   gcnt  = (int*)  alloc((size_t)NB * 4);
    int*   bbase = (int*)  alloc((size_t)NB * 4);
    int*   off   = (int*)  alloc((size_t)(N + 1) * 4);
    int*   srcs  = (int*)  alloc((size_t)E * 4);
    unsigned int* tmp = (unsigned int*)alloc((size_t)NB * BCAP * 4);
    unsigned short* wt1 = (unsigned short*)alloc(128 * 128 * 2);
    unsigned short* wt2 = (unsigned short*)alloc(64 * 128 * 2);
    unsigned short* hs1 = (unsigned short*)alloc((size_t)N * DIN * 2);
    unsigned short* h1p = (unsigned short*)alloc((size_t)N * DIN * 2);
    unsigned short* hs2 = (unsigned short*)alloc((size_t)N * NCLS * 2);

    // W prep + CSR build
    wprep_k<<<64, 256, 0, stream>>>(W1, W2, wt1, wt2);
    hipMemsetAsync(gcnt, 0, (size_t)NB * 4, stream);
    binA_k<<<(E + 4095) / 4096, 256, 0, stream>>>(ei, gcnt, tmp, E, NB);
    scanb_k<<<1, 512, 0, stream>>>(gcnt, bbase, NB);
    binB_k<<<NB, 256, 0, stream>>>(tmp, gcnt, bbase, off, dinv, srcs, N, E);

    // layer 1
    mgemm_k<DIN, true><<<(N + 127) / 128, 256, 0, stream>>>(x, wt1, dinv, hs1, N);
    gather1_k<<<(N + 3) / 4, 256, 0, stream>>>(hs1, off, srcs, dinv, b1, h1p, N);

    // layer 2
    mgemm_k<NCLS, false><<<(N + 127) / 128, 256, 0, stream>>>(h1p, wt2, dinv, hs2, N);
    gather2_k<<<(N + 7) / 8, 256, 0, stream>>>(hs2, off, srcs, dinv, b2, out, N);
}